// Round 1
// baseline (85.285 us; speedup 1.0000x reference)
//
#include <hip/hip_runtime.h>

#define HH 32
#define WW 32
#define NB 16
#define NPOS 512
#define TILE 8            // (h,w) positions per block (contiguous in w, same row)
#define PPAD 516          // padded p-stride in LDS floats: 516 % 32 == 4 -> conflict-free float4 reads

__global__ __launch_bounds__(128) void asic_layer(
    const float* __restrict__ src,   // (16,32,32) current state
    const float* __restrict__ tg,    // (512,32,32) toggle gates for this layer
    float* __restrict__ dst)         // (16,32,32) next state
{
    __shared__ float lut[TILE * PPAD];

    const int t    = threadIdx.x;    // 0..127
    const int hw0  = blockIdx.x * TILE;

    // ---- stage sigmoid(tg) for our 8 positions into LDS (once per entry; shared by 16 batches)
    #pragma unroll
    for (int k = 0; k < 32; ++k) {
        int f   = t + 128 * k;       // 0..4095
        int p   = f >> 3;
        int hwl = f & 7;
        float g = tg[p * (HH * WW) + hw0 + hwl];
        lut[hwl * PPAD + p] = 1.0f / (1.0f + __expf(-g));
    }
    __syncthreads();

    const int b   = t >> 3;          // batch 0..15
    const int hwl = t & 7;
    const int h   = hw0 >> 5;
    const int w   = (hw0 & 31) + hwl;

    // ---- gather 3x3 wrapped window: c[3i+j] = src[b, (h+i)%32, (w+j-1)%32]
    float c[9];
    const float* sb = src + b * (HH * WW);
    #pragma unroll
    for (int i = 0; i < 3; ++i) {
        int row = ((h + i) & 31) * 32;
        #pragma unroll
        for (int j = 0; j < 3; ++j) {
            c[3 * i + j] = sb[row + ((w + j - 1 + 32) & 31)];
        }
    }

    // ---- v[lo]: product over m=4..8 (MSB-first within lo)
    float v[32];
    {
        float a2[2], a4[4], a8[8], a16[16];
        a2[0] = 1.0f - c[4]; a2[1] = c[4];
        #pragma unroll
        for (int q = 0; q < 2; ++q)  { a4[2*q]  = a2[q]  * (1.0f - c[5]); a4[2*q+1]  = a2[q]  * c[5]; }
        #pragma unroll
        for (int q = 0; q < 4; ++q)  { a8[2*q]  = a4[q]  * (1.0f - c[6]); a8[2*q+1]  = a4[q]  * c[6]; }
        #pragma unroll
        for (int q = 0; q < 8; ++q)  { a16[2*q] = a8[q]  * (1.0f - c[7]); a16[2*q+1] = a8[q]  * c[7]; }
        #pragma unroll
        for (int q = 0; q < 16; ++q) { v[2*q]   = a16[q] * (1.0f - c[8]); v[2*q+1]   = a16[q] * c[8]; }
    }
    // ---- u[hi]: product over m=0..3 (MSB-first within hi)
    float u[16];
    {
        float a2[2], a4[4], a8[8];
        a2[0] = 1.0f - c[0]; a2[1] = c[0];
        #pragma unroll
        for (int q = 0; q < 2; ++q) { a4[2*q] = a2[q] * (1.0f - c[1]); a4[2*q+1] = a2[q] * c[1]; }
        #pragma unroll
        for (int q = 0; q < 4; ++q) { a8[2*q] = a4[q] * (1.0f - c[2]); a8[2*q+1] = a4[q] * c[2]; }
        #pragma unroll
        for (int q = 0; q < 8; ++q) { u[2*q]  = a8[q] * (1.0f - c[3]); u[2*q+1]  = a8[q] * c[3]; }
    }

    // ---- acc = sum_hi u[hi] * sum_lo v[lo] * lut[hwl][hi*32+lo]   (float4 LDS reads)
    const float4* lut4 = (const float4*)(lut + hwl * PPAD);   // hwl*516*4 bytes: 16B aligned
    float acc = 0.0f;
    #pragma unroll
    for (int hi = 0; hi < 16; ++hi) {
        float ps = 0.0f;
        #pragma unroll
        for (int l4 = 0; l4 < 8; ++l4) {
            float4 L = lut4[hi * 8 + l4];
            ps += L.x * v[4*l4] + L.y * v[4*l4+1] + L.z * v[4*l4+2] + L.w * v[4*l4+3];
        }
        acc += u[hi] * ps;
    }

    acc = fminf(fmaxf(acc, 0.0f), 1.0f);
    dst[b * (HH * WW) + h * 32 + w] = acc;
}

extern "C" void kernel_launch(void* const* d_in, const int* in_sizes, int n_in,
                              void* d_out, int out_size, void* d_ws, size_t ws_size,
                              hipStream_t stream) {
    const float* x  = (const float*)d_in[0];   // (16,32,32)
    const float* tg = (const float*)d_in[1];   // (4,512,32,32)
    float* out = (float*)d_out;                // (16,32,32)
    float* ws  = (float*)d_ws;                 // needs 64 KB

    const int grid = (HH * WW) / TILE;         // 128 blocks
    const size_t L = (size_t)NPOS * HH * WW;   // elems per layer of tg

    // ping-pong: x -> ws -> out -> ws -> out
    asic_layer<<<grid, 128, 0, stream>>>(x,   tg + 0 * L, ws);
    asic_layer<<<grid, 128, 0, stream>>>(ws,  tg + 1 * L, out);
    asic_layer<<<grid, 128, 0, stream>>>(out, tg + 2 * L, ws);
    asic_layer<<<grid, 128, 0, stream>>>(ws,  tg + 3 * L, out);
}